// Round 1
// baseline (649.443 us; speedup 1.0000x reference)
//
#include <hip/hip_runtime.h>
#include <float.h>
#include <math.h>

#define HH 224
#define WW 224
#define PLANE (HH*WW)
#define FRAME (3*HH*WW)   // 150528
#define LFR 64            // frames per batch
#define NP 63             // pairs per batch
#define NB 8              // batch
#define NM 16             // MAX_NUM_FRAME
#define EPSV 1e-6f

// ---------------- Stage 1: per-pair diff score ----------------
// diff_score[b,l] = sum_{i,j} | w * box7x7( sum_c (x[b,l,c]-x[b,l+1,c]) )(i,j) + eps |
// One block per (b,l) pair. Threads 0..223 own columns. 4 rows per phase.
__global__ __launch_bounds__(256) void diff_kernel(
    const float* __restrict__ x, const float* __restrict__ cw,
    float* __restrict__ ds)
{
    const int pair = blockIdx.x;
    const int b = pair / NP;
    const int l = pair - b * NP;
    const float* f0 = x + (size_t)(b * LFR + l) * FRAME;
    const float* f1 = f0 + FRAME;
    const float w = cw[0];

    __shared__ float dBuf[4][WW];       // pair-diff channel-sum rows (current phase)
    __shared__ float Hring[16][WW];     // horizontal 7-box rows, ring of 16

    const int tid = threadIdx.x;
    const bool act = tid < WW;
    float acc = 0.f;

    // --- helper phase: compute H rows [r0, r1] (inclusive, caller clamps to <HH)
    // Implemented inline twice (prologue rows 0..2, then main loop).

    // Prologue: H rows 0..2
    {
        float dval[3];
        if (act) {
            #pragma unroll
            for (int k = 0; k < 3; ++k) {
                int off = k * WW + tid;
                float a0 = f0[off], a1 = f0[PLANE + off], a2 = f0[2*PLANE + off];
                float b0 = f1[off], b1 = f1[PLANE + off], b2 = f1[2*PLANE + off];
                dval[k] = (a0 - b0) + (a1 - b1) + (a2 - b2);
            }
            #pragma unroll
            for (int k = 0; k < 3; ++k) dBuf[k][tid] = dval[k];
        }
        __syncthreads();
        if (act) {
            #pragma unroll
            for (int k = 0; k < 3; ++k) {
                float h = 0.f;
                #pragma unroll
                for (int dj = -3; dj <= 3; ++dj) {
                    int j = tid + dj;
                    if (j >= 0 && j < WW) h += dBuf[k][j];
                }
                Hring[k & 15][tid] = h;
            }
        }
        __syncthreads();
    }

    // Main loop: 4 output rows per phase
    for (int i0 = 0; i0 < HH; i0 += 4) {
        const int rFirst = i0 + 3;                       // first new H row
        const int rLast  = (i0 + 6 < HH) ? (i0 + 6) : (HH - 1); // last new H row
        if (rFirst < HH) {
            float dval[4];
            if (act) {
                #pragma unroll
                for (int k = 0; k < 4; ++k) {
                    int r = rFirst + k;
                    if (r <= rLast) {
                        int off = r * WW + tid;
                        float a0 = f0[off], a1 = f0[PLANE + off], a2 = f0[2*PLANE + off];
                        float b0 = f1[off], b1 = f1[PLANE + off], b2 = f1[2*PLANE + off];
                        dval[k] = (a0 - b0) + (a1 - b1) + (a2 - b2);
                    }
                }
                #pragma unroll
                for (int k = 0; k < 4; ++k)
                    if (rFirst + k <= rLast) dBuf[k][tid] = dval[k];
            }
            __syncthreads();
            if (act) {
                #pragma unroll
                for (int k = 0; k < 4; ++k) {
                    int r = rFirst + k;
                    if (r <= rLast) {
                        float h = 0.f;
                        #pragma unroll
                        for (int dj = -3; dj <= 3; ++dj) {
                            int j = tid + dj;
                            if (j >= 0 && j < WW) h += dBuf[k][j];
                        }
                        Hring[r & 15][tid] = h;
                    }
                }
            }
            __syncthreads();
        }
        if (act) {
            #pragma unroll
            for (int k = 0; k < 4; ++k) {
                int i = i0 + k;
                if (i < HH) {
                    int r0 = i - 3; if (r0 < 0) r0 = 0;
                    int r1 = i + 3; if (r1 > HH - 1) r1 = HH - 1;
                    float v = 0.f;
                    for (int r = r0; r <= r1; ++r) v += Hring[r & 15][tid];
                    acc += fabsf(w * v + EPSV);
                }
            }
        }
    }

    // Block reduction (inactive threads hold 0)
    #pragma unroll
    for (int off = 32; off >= 1; off >>= 1)
        acc += __shfl_down(acc, off, 64);
    __shared__ float red[4];
    const int wave = tid >> 6;
    if ((tid & 63) == 0) red[wave] = acc;
    __syncthreads();
    if (tid == 0)
        ds[pair] = red[0] + red[1] + red[2] + red[3];
}

// ---------------- Stage 2: dsp -> cumsum -> argmin indices ----------------
// One 64-lane wave per batch element.
__global__ __launch_bounds__(64) void select_kernel(
    const float* __restrict__ ds, int* __restrict__ idx)
{
    const int b = blockIdx.x;
    const int lane = threadIdx.x;
    float v = (lane < NP) ? sqrtf(ds[b * NP + lane]) : 0.f;  // power(ds, 0.5)

    // total sum (butterfly)
    float tot = v;
    #pragma unroll
    for (int off = 1; off < 64; off <<= 1)
        tot += __shfl_xor(tot, off, 64);

    // inclusive scan
    float scan = v;
    #pragma unroll
    for (int off = 1; off < 64; off <<= 1) {
        float t = __shfl_up(scan, off, 64);
        if (lane >= off) scan += t;
    }
    const float cum = scan / tot;

    const float interval = 1.0f / (NM - 1);
    for (int m = 0; m < NM; ++m) {
        const float target = (float)m * interval;
        float bv = (lane < NP) ? fabsf(cum - target) : FLT_MAX;
        int bi = lane;
        // lexicographic (value, index) min -> first-occurrence argmin
        #pragma unroll
        for (int off = 1; off < 64; off <<= 1) {
            float ov = __shfl_xor(bv, off, 64);
            int oi = __shfl_xor(bi, off, 64);
            if (ov < bv || (ov == bv && oi < bi)) { bv = ov; bi = oi; }
        }
        if (lane == 0) idx[b * NM + m] = bi;
    }
}

// ---------------- Stage 3: gather selected frames ----------------
__global__ __launch_bounds__(256) void gather_kernel(
    const float* __restrict__ x, const int* __restrict__ idx,
    float* __restrict__ out)
{
    const int f = blockIdx.y;            // b*NM + m, 0..127
    const int b = f >> 4;
    const int i = blockIdx.x * 256 + threadIdx.x;   // float4 index in frame
    const int id = idx[f];
    const float4* src = (const float4*)(x + (size_t)(b * LFR + id) * FRAME);
    float4* dst = (float4*)(out + (size_t)f * FRAME);
    dst[i] = src[i];
}

extern "C" void kernel_launch(void* const* d_in, const int* in_sizes, int n_in,
                              void* d_out, int out_size, void* d_ws, size_t ws_size,
                              hipStream_t stream) {
    const float* x  = (const float*)d_in[0];
    const float* cw = (const float*)d_in[1];
    // conv_b is identically zero and cancels in the pair difference.
    float* ds  = (float*)d_ws;                       // 504 floats
    int*   idx = (int*)((char*)d_ws + 4096);         // 128 ints

    hipLaunchKernelGGL(diff_kernel, dim3(NB * NP), dim3(256), 0, stream, x, cw, ds);
    hipLaunchKernelGGL(select_kernel, dim3(NB), dim3(64), 0, stream, ds, idx);
    // FRAME/4 = 37632 float4s = 147 * 256
    hipLaunchKernelGGL(gather_kernel, dim3(147, NB * NM), dim3(256), 0, stream,
                       x, idx, (float*)d_out);
}

// Round 2
// 500.485 us; speedup vs baseline: 1.2976x; 1.2976x over previous
//
#include <hip/hip_runtime.h>
#include <float.h>
#include <math.h>

#define HH 224
#define WW 224
#define PLANE (HH*WW)
#define FRAME (3*HH*WW)   // 150528
#define LFR 64            // frames per batch
#define NP 63             // pairs per batch
#define NB 8              // batch
#define NM 16             // MAX_NUM_FRAME
#define EPSV 1e-6f

#define RSLAB 32          // output rows per slab
#define NSLAB (HH / RSLAB)  // 7
#define DROWS (RSLAB + 6)   // 38 input D-rows incl. halo

// ---------------- Stage 1: per-pair-slab diff score ----------------
// D(r,c)   = sum_c (x[b,l] - x[b,l+1]) at (r,c)        (zero outside image)
// V(i,c)   = sum_{di=-3..3} D(i+di, c)                  (vertical box, registers)
// out(i,c) = | w * sum_{dj=-3..3} V(i, c+dj) + eps |    (horizontal box via LDS)
// One block per (slab, pair). Threads 0..223 own columns. ONE barrier.
__global__ __launch_bounds__(256) void diff_kernel(
    const float* __restrict__ x, const float* __restrict__ cw,
    float* __restrict__ dsp)
{
    const int slab = blockIdx.x;         // 0..6
    const int pair = blockIdx.y;         // 0..503
    const int b = pair / NP;
    const int l = pair - b * NP;
    const float* f0 = x + (size_t)(b * LFR + l) * FRAME;
    const float* f1 = f0 + FRAME;
    const float w = cw[0];

    const int i0 = slab * RSLAB;         // first output row
    const int rBase = i0 - 3;            // first D row (may be negative)

    __shared__ float Vbuf[RSLAB][WW];    // vertical-box rows, 28.7 KB

    const int tid = threadIdx.x;
    const bool act = tid < WW;
    float acc = 0.f;

    if (act) {
        // Pass A: all D rows for this column straight into registers.
        float d[DROWS];
        #pragma unroll
        for (int k = 0; k < DROWS; ++k) {
            const int r = rBase + k;
            float v = 0.f;
            if (r >= 0 && r < HH) {
                const int off = r * WW + tid;
                v = (f0[off]           - f1[off])
                  + (f0[PLANE + off]   - f1[PLANE + off])
                  + (f0[2*PLANE + off] - f1[2*PLANE + off]);
            }
            d[k] = v;
        }
        // Vertical 7-box into LDS (output row i0+ko uses d[ko..ko+6]).
        #pragma unroll
        for (int ko = 0; ko < RSLAB; ++ko) {
            float v = d[ko] + d[ko+1] + d[ko+2] + d[ko+3]
                    + d[ko+4] + d[ko+5] + d[ko+6];
            Vbuf[ko][tid] = v;
        }
    }
    __syncthreads();

    if (act) {
        // Pass B: horizontal 7-box + abs-accumulate.
        #pragma unroll 4
        for (int ko = 0; ko < RSLAB; ++ko) {
            float s = 0.f;
            #pragma unroll
            for (int dj = -3; dj <= 3; ++dj) {
                const int j = tid + dj;
                if (j >= 0 && j < WW) s += Vbuf[ko][j];
            }
            acc += fabsf(w * s + EPSV);
        }
    }

    // Block reduction (inactive threads hold 0)
    #pragma unroll
    for (int off = 32; off >= 1; off >>= 1)
        acc += __shfl_down(acc, off, 64);
    __shared__ float red[4];
    const int wave = tid >> 6;
    if ((tid & 63) == 0) red[wave] = acc;
    __syncthreads();
    if (tid == 0)
        dsp[pair * NSLAB + slab] = red[0] + red[1] + red[2] + red[3];
}

// ---------------- Stage 2: dsp -> cumsum -> argmin indices ----------------
// One 64-lane wave per batch element.
__global__ __launch_bounds__(64) void select_kernel(
    const float* __restrict__ dsp, int* __restrict__ idx)
{
    const int b = blockIdx.x;
    const int lane = threadIdx.x;
    float v = 0.f;
    if (lane < NP) {
        float s = 0.f;
        #pragma unroll
        for (int k = 0; k < NSLAB; ++k) s += dsp[(b * NP + lane) * NSLAB + k];
        v = sqrtf(s);                    // power(diff_score, 0.5)
    }

    // total sum (butterfly)
    float tot = v;
    #pragma unroll
    for (int off = 1; off < 64; off <<= 1)
        tot += __shfl_xor(tot, off, 64);

    // inclusive scan
    float scan = v;
    #pragma unroll
    for (int off = 1; off < 64; off <<= 1) {
        float t = __shfl_up(scan, off, 64);
        if (lane >= off) scan += t;
    }
    const float cum = scan / tot;

    const float interval = 1.0f / (NM - 1);
    for (int m = 0; m < NM; ++m) {
        const float target = (float)m * interval;
        float bv = (lane < NP) ? fabsf(cum - target) : FLT_MAX;
        int bi = lane;
        // lexicographic (value, index) min -> first-occurrence argmin
        #pragma unroll
        for (int off = 1; off < 64; off <<= 1) {
            float ov = __shfl_xor(bv, off, 64);
            int oi = __shfl_xor(bi, off, 64);
            if (ov < bv || (ov == bv && oi < bi)) { bv = ov; bi = oi; }
        }
        if (lane == 0) idx[b * NM + m] = bi;
    }
}

// ---------------- Stage 3: gather selected frames ----------------
// 7 float4 per thread; FRAME/4 = 37632 = 21 * 256 * 7.
__global__ __launch_bounds__(256) void gather_kernel(
    const float* __restrict__ x, const int* __restrict__ idx,
    float* __restrict__ out)
{
    const int f = blockIdx.y;            // b*NM + m, 0..127
    const int b = f >> 4;
    const int id = idx[f];
    const float4* src = (const float4*)(x + (size_t)(b * LFR + id) * FRAME);
    float4* dst = (float4*)(out + (size_t)f * FRAME);
    const int i = blockIdx.x * 256 + threadIdx.x;
    #pragma unroll
    for (int k = 0; k < 7; ++k)
        dst[i + k * (21 * 256)] = src[i + k * (21 * 256)];
}

extern "C" void kernel_launch(void* const* d_in, const int* in_sizes, int n_in,
                              void* d_out, int out_size, void* d_ws, size_t ws_size,
                              hipStream_t stream) {
    const float* x  = (const float*)d_in[0];
    const float* cw = (const float*)d_in[1];
    // conv_b is identically zero and cancels in the pair difference.
    float* dsp = (float*)d_ws;                       // 504*7 floats
    int*   idx = (int*)((char*)d_ws + 16384);        // 128 ints

    hipLaunchKernelGGL(diff_kernel, dim3(NSLAB, NB * NP), dim3(256), 0, stream,
                       x, cw, dsp);
    hipLaunchKernelGGL(select_kernel, dim3(NB), dim3(64), 0, stream, dsp, idx);
    hipLaunchKernelGGL(gather_kernel, dim3(21, NB * NM), dim3(256), 0, stream,
                       x, idx, (float*)d_out);
}

// Round 3
// 467.230 us; speedup vs baseline: 1.3900x; 1.0712x over previous
//
#include <hip/hip_runtime.h>
#include <float.h>
#include <math.h>

#define HH 224
#define WW 224
#define PLANE (HH*WW)
#define FRAME (3*HH*WW)   // 150528
#define LFR 64            // frames per batch
#define NP 63             // pairs per batch
#define NB 8              // batch
#define NM 16             // MAX_NUM_FRAME
#define EPSV 1e-6f

#define RSLAB 32            // output rows per slab
#define NSLAB (HH / RSLAB)  // 7
#define DROWS (RSLAB + 6)   // 38 D-rows incl. halo
#define LDW 232             // padded LDS row: 4 zero | 224 data | 4 zero (16B-aligned quads)
#define NQ 56               // float4 quads per row (224/4)
#define UNITS (DROWS * NQ)  // 2128 load units per block

// ---------------- Stage 1: per-pair-slab diff score ----------------
// D(r,c) = sum_ch (x[b,l]-x[b,l+1])   (zero outside image; zero-padded cols in LDS)
// out(i,c) = | w * sum_{di,dj in [-3,3]} D(i+di, c+dj) + eps |
__global__ __launch_bounds__(256) void diff_kernel(
    const float* __restrict__ x, const float* __restrict__ cw,
    float* __restrict__ dsp)
{
    const int slab = blockIdx.x;         // 0..6
    const int pair = blockIdx.y;         // 0..503
    const int b = pair / NP;
    const int l = pair - b * NP;
    const float* f0 = x + (size_t)(b * LFR + l) * FRAME;
    const float* f1 = f0 + FRAME;
    const float w = cw[0];

    const int rBase = slab * RSLAB - 3;  // global row of local D-row 0

    __shared__ float Dl[DROWS][LDW];     // 35.3 KB
    __shared__ float red[4];

    const int tid = threadIdx.x;

    // Zero the 4-col pads on both sides (38 rows x 2 sides, float4 each).
    if (tid < 2 * DROWS) {
        const int r = tid >> 1;
        const int col = (tid & 1) ? (LDW - 4) : 0;
        *(float4*)&Dl[r][col] = make_float4(0.f, 0.f, 0.f, 0.f);
    }

    // Phase A: flat cooperative float4 load loop, no per-row branches on loads.
    for (int u = tid; u < UNITS; u += 256) {
        const int r  = u / NQ;           // local D-row
        const int cq = u - r * NQ;       // column quad
        const int gr = rBase + r;        // global row
        float4 v = make_float4(0.f, 0.f, 0.f, 0.f);
        if (gr >= 0 && gr < HH) {
            const int off = (gr * WW + cq * 4) >> 2;   // float4 index
            const float4* p0 = (const float4*)f0;
            const float4* p1 = (const float4*)f1;
            const float4 a0 = p0[off];
            const float4 a1 = p0[off + PLANE/4];
            const float4 a2 = p0[off + 2*PLANE/4];
            const float4 b0 = p1[off];
            const float4 b1 = p1[off + PLANE/4];
            const float4 b2 = p1[off + 2*PLANE/4];
            v.x = (a0.x - b0.x) + (a1.x - b1.x) + (a2.x - b2.x);
            v.y = (a0.y - b0.y) + (a1.y - b1.y) + (a2.y - b2.y);
            v.z = (a0.z - b0.z) + (a1.z - b1.z) + (a2.z - b2.z);
            v.w = (a0.w - b0.w) + (a1.w - b1.w) + (a2.w - b2.w);
        }
        *(float4*)&Dl[r][4 + cq * 4] = v;
    }
    __syncthreads();

    // Phase B: per-column 7x7 box via direct sums from padded LDS.
    float acc = 0.f;
    if (tid < WW) {
        const int base = 4 + tid;        // this column in padded LDS coords
        float hring[8];
        #pragma unroll
        for (int r = 0; r < DROWS; ++r) {
            float h = 0.f;
            #pragma unroll
            for (int k = 0; k < 7; ++k) h += Dl[r][base - 3 + k];
            hring[r & 7] = h;
            if (r >= 6) {
                float v = 0.f;
                #pragma unroll
                for (int k = 0; k < 7; ++k) v += hring[(r - 6 + k) & 7];
                acc += fabsf(w * v + EPSV);
            }
        }
    }

    // Block reduction (inactive threads hold 0)
    #pragma unroll
    for (int off = 32; off >= 1; off >>= 1)
        acc += __shfl_down(acc, off, 64);
    const int wave = tid >> 6;
    if ((tid & 63) == 0) red[wave] = acc;
    __syncthreads();
    if (tid == 0)
        dsp[pair * NSLAB + slab] = red[0] + red[1] + red[2] + red[3];
}

// ---------------- Stage 2: dsp -> cumsum -> argmin indices ----------------
__global__ __launch_bounds__(64) void select_kernel(
    const float* __restrict__ dsp, int* __restrict__ idx)
{
    const int b = blockIdx.x;
    const int lane = threadIdx.x;
    float v = 0.f;
    if (lane < NP) {
        float s = 0.f;
        #pragma unroll
        for (int k = 0; k < NSLAB; ++k) s += dsp[(b * NP + lane) * NSLAB + k];
        v = sqrtf(s);                    // power(diff_score, 0.5)
    }

    float tot = v;
    #pragma unroll
    for (int off = 1; off < 64; off <<= 1)
        tot += __shfl_xor(tot, off, 64);

    float scan = v;
    #pragma unroll
    for (int off = 1; off < 64; off <<= 1) {
        float t = __shfl_up(scan, off, 64);
        if (lane >= off) scan += t;
    }
    const float cum = scan / tot;

    const float interval = 1.0f / (NM - 1);
    for (int m = 0; m < NM; ++m) {
        const float target = (float)m * interval;
        float bv = (lane < NP) ? fabsf(cum - target) : FLT_MAX;
        int bi = lane;
        #pragma unroll
        for (int off = 1; off < 64; off <<= 1) {
            float ov = __shfl_xor(bv, off, 64);
            int oi = __shfl_xor(bi, off, 64);
            if (ov < bv || (ov == bv && oi < bi)) { bv = ov; bi = oi; }
        }
        if (lane == 0) idx[b * NM + m] = bi;
    }
}

// ---------------- Stage 3: gather selected frames ----------------
// 7 float4 per thread; FRAME/4 = 37632 = 21 * 256 * 7.
__global__ __launch_bounds__(256) void gather_kernel(
    const float* __restrict__ x, const int* __restrict__ idx,
    float* __restrict__ out)
{
    const int f = blockIdx.y;            // b*NM + m, 0..127
    const int b = f >> 4;
    const int id = idx[f];
    const float4* src = (const float4*)(x + (size_t)(b * LFR + id) * FRAME);
    float4* dst = (float4*)(out + (size_t)f * FRAME);
    const int i = blockIdx.x * 256 + threadIdx.x;
    #pragma unroll
    for (int k = 0; k < 7; ++k)
        dst[i + k * (21 * 256)] = src[i + k * (21 * 256)];
}

extern "C" void kernel_launch(void* const* d_in, const int* in_sizes, int n_in,
                              void* d_out, int out_size, void* d_ws, size_t ws_size,
                              hipStream_t stream) {
    const float* x  = (const float*)d_in[0];
    const float* cw = (const float*)d_in[1];
    // conv_b is identically zero and cancels in the pair difference.
    float* dsp = (float*)d_ws;                       // 504*7 floats
    int*   idx = (int*)((char*)d_ws + 16384);        // 128 ints

    hipLaunchKernelGGL(diff_kernel, dim3(NSLAB, NB * NP), dim3(256), 0, stream,
                       x, cw, dsp);
    hipLaunchKernelGGL(select_kernel, dim3(NB), dim3(64), 0, stream, dsp, idx);
    hipLaunchKernelGGL(gather_kernel, dim3(21, NB * NM), dim3(256), 0, stream,
                       x, idx, (float*)d_out);
}